// Round 4
// baseline (2227.512 us; speedup 1.0000x reference)
//
#include <hip/hip_runtime.h>
#include <hip/hip_bf16.h>

#define N_NODES 100000
#define F_IN    512
#define HID     256
#define C_CLS   40
#define E_EDGES 1600000
#define K_STEPS 10

typedef __attribute__((ext_vector_type(8))) short bf16x8;
typedef __attribute__((ext_vector_type(4))) float f32x4;

union frag8 { bf16x8 v; unsigned short u[8]; uint4 q; };

__device__ inline unsigned short f2bf(float v) {
    union { __hip_bfloat16 b; unsigned short u; } c;
    c.b = __float2bfloat16(v);
    return c.u;
}
__device__ inline float bf2f(unsigned short u) {
    union { __hip_bfloat16 b; unsigned short u; } c;
    c.u = u;
    return __bfloat162float(c.b);
}
// split fp32 -> hi + lo bf16 (RNE both): v ~= hi + lo, err ~2^-17|v|
__device__ inline void splitbf(float v, unsigned short& hi, unsigned short& lo) {
    hi = f2bf(v);
    lo = f2bf(v - bf2f(hi));
}

// ---------------------------------------------------------------- dtype sniff
// flags[0]=x_is_f32  flags[1]=w_is_f32  flags[2]=edge_is_i32
__global__ void sniff_kernel(const unsigned* __restrict__ Xu,
                             const unsigned* __restrict__ W1u,
                             const unsigned* __restrict__ EIu,
                             int* __restrict__ flags)
{
    __shared__ int cnt[3];
    int t = threadIdx.x;
    if (t < 3) cnt[t] = 0;
    __syncthreads();
    // fp32 N(0,~1)-ish data: exponent field in [64,170]; bf16-pair words: ~never
    unsigned xe = (Xu[t] >> 23) & 0xFF;
    if (xe >= 64 && xe <= 170) atomicAdd(&cnt[0], 1);
    unsigned we = (W1u[t] >> 23) & 0xFF;
    if (we >= 64 && we <= 170) atomicAdd(&cnt[1], 1);
    // int32 edges: odd words are src values (rarely 0); int64: always 0
    if (EIu[2 * t + 1] != 0) atomicAdd(&cnt[2], 1);
    __syncthreads();
    if (t == 0) {
        flags[0] = cnt[0] >= 200;
        flags[1] = cnt[1] >= 200;
        flags[2] = cnt[2] >= 8;
    }
}

// ---------------------------------------------------------------- canonical weights
// W1T_hi/lo [256][512], W2T_hi/lo [48][256] (cols>=40 zero), b1c[256], b2c[48] fp32
__global__ void canonw_kernel(const void* __restrict__ W1_, const void* __restrict__ W2_,
                              const void* __restrict__ b1_, const void* __restrict__ b2_,
                              const int* __restrict__ flags,
                              unsigned short* __restrict__ W1T_hi, unsigned short* __restrict__ W1T_lo,
                              unsigned short* __restrict__ W2T_hi, unsigned short* __restrict__ W2T_lo,
                              float* __restrict__ b1c, float* __restrict__ b2c)
{
    const bool wf32 = flags[1] != 0;
    int i = blockIdx.x * 256 + threadIdx.x;
    if (i < 131072) {                       // W1T
        int n = i >> 9, k = i & 511;
        float v = wf32 ? ((const float*)W1_)[k * HID + n]
                       : bf2f(((const unsigned short*)W1_)[k * HID + n]);
        unsigned short hi, lo; splitbf(v, hi, lo);
        W1T_hi[i] = hi; W1T_lo[i] = lo;
    }
    int j = i - 131072;
    if (j >= 0 && j < 48 * 256) {           // W2T
        int n = j >> 8, k = j & 255;
        float v = 0.f;
        if (n < C_CLS) v = wf32 ? ((const float*)W2_)[k * C_CLS + n]
                                : bf2f(((const unsigned short*)W2_)[k * C_CLS + n]);
        unsigned short hi, lo; splitbf(v, hi, lo);
        W2T_hi[j] = hi; W2T_lo[j] = lo;
    }
    int l = i - 131072 - 12288;
    if (l >= 0 && l < 256)
        b1c[l] = wf32 ? ((const float*)b1_)[l] : bf2f(((const unsigned short*)b1_)[l]);
    if (l >= 256 && l < 256 + 48) {
        int c = l - 256;
        b2c[c] = (c < C_CLS) ? (wf32 ? ((const float*)b2_)[c]
                                     : bf2f(((const unsigned short*)b2_)[c])) : 0.f;
    }
}

// ---------------------------------------------------------------- fused MLP (bf16x3)
// 48 rows/block; phase1: h1=relu(X@W1+b1) -> LDS hi/lo; phase2: relu(h1@W2+b2) -> H2,Za (fp32)
__global__ __launch_bounds__(256) void mlp48_kernel(
    const void* __restrict__ X_,
    const unsigned short* __restrict__ W1T_hi, const unsigned short* __restrict__ W1T_lo,
    const unsigned short* __restrict__ W2T_hi, const unsigned short* __restrict__ W2T_lo,
    const float* __restrict__ b1c, const float* __restrict__ b2c,
    const int* __restrict__ flags,
    float* __restrict__ H2, float* __restrict__ Za)
{
    __shared__ __align__(16) unsigned short h1hi[48 * 264];
    __shared__ __align__(16) unsigned short h1lo[48 * 264];

    const int tid = threadIdx.x, lane = tid & 63, wave = tid >> 6;
    const int row16 = lane & 15, quad = lane >> 4;
    const int m0 = blockIdx.x * 48;
    const bool xf32 = flags[0] != 0;

    f32x4 acc[3][4];
    const f32x4 z4 = {0.f, 0.f, 0.f, 0.f};
#pragma unroll
    for (int i = 0; i < 3; i++)
#pragma unroll
        for (int j = 0; j < 4; j++) acc[i][j] = z4;

    for (int k0 = 0; k0 < F_IN; k0 += 32) {
        frag8 Ah[3], Al[3], Bh[4], Bl[4];
#pragma unroll
        for (int i = 0; i < 3; i++) {
            int gm = m0 + i * 16 + row16; if (gm >= N_NODES) gm = N_NODES - 1;
            if (xf32) {
                const float* p = (const float*)X_ + (size_t)gm * F_IN + k0 + quad * 8;
                float4 f0 = *(const float4*)p;
                float4 f1 = *(const float4*)(p + 4);
                float vv[8] = {f0.x, f0.y, f0.z, f0.w, f1.x, f1.y, f1.z, f1.w};
#pragma unroll
                for (int j = 0; j < 8; j++) splitbf(vv[j], Ah[i].u[j], Al[i].u[j]);
            } else {
                const unsigned short* p = (const unsigned short*)X_ + (size_t)gm * F_IN + k0 + quad * 8;
                Ah[i].q = *(const uint4*)p;
#pragma unroll
                for (int j = 0; j < 8; j++) Al[i].u[j] = 0;
            }
        }
#pragma unroll
        for (int t = 0; t < 4; t++) {
            int col = wave * 64 + t * 16 + row16;
            Bh[t].q = *(const uint4*)(W1T_hi + (size_t)col * F_IN + k0 + quad * 8);
            Bl[t].q = *(const uint4*)(W1T_lo + (size_t)col * F_IN + k0 + quad * 8);
        }
#pragma unroll
        for (int i = 0; i < 3; i++)
#pragma unroll
            for (int t = 0; t < 4; t++) {
                acc[i][t] = __builtin_amdgcn_mfma_f32_16x16x32_bf16(Ah[i].v, Bh[t].v, acc[i][t], 0, 0, 0);
                acc[i][t] = __builtin_amdgcn_mfma_f32_16x16x32_bf16(Ah[i].v, Bl[t].v, acc[i][t], 0, 0, 0);
                acc[i][t] = __builtin_amdgcn_mfma_f32_16x16x32_bf16(Al[i].v, Bh[t].v, acc[i][t], 0, 0, 0);
            }
    }

    // epilogue 1: bias+relu, split -> LDS. C/D: col=lane&15, row=quad*4+reg
#pragma unroll
    for (int j = 0; j < 4; j++) {
        int col = wave * 64 + j * 16 + row16;
        float bias = b1c[col];
#pragma unroll
        for (int i = 0; i < 3; i++)
#pragma unroll
            for (int r = 0; r < 4; r++) {
                int lm = i * 16 + quad * 4 + r;
                float v = acc[i][j][r] + bias;
                v = v > 0.f ? v : 0.f;
                unsigned short hi, lo; splitbf(v, hi, lo);
                h1hi[lm * 264 + col] = hi;
                h1lo[lm * 264 + col] = lo;
            }
    }
    __syncthreads();

    // phase 2: waves 0..2 -> rows wave*16..+15, cols 0..47
    if (wave < 3) {
        f32x4 a2[3];
        a2[0] = z4; a2[1] = z4; a2[2] = z4;
        for (int k0 = 0; k0 < HID; k0 += 32) {
            frag8 Ah2, Al2;
            Ah2.v = *(const bf16x8*)(h1hi + (wave * 16 + row16) * 264 + k0 + quad * 8);
            Al2.v = *(const bf16x8*)(h1lo + (wave * 16 + row16) * 264 + k0 + quad * 8);
#pragma unroll
            for (int t = 0; t < 3; t++) {
                frag8 Bh2, Bl2;
                Bh2.q = *(const uint4*)(W2T_hi + (t * 16 + row16) * HID + k0 + quad * 8);
                Bl2.q = *(const uint4*)(W2T_lo + (t * 16 + row16) * HID + k0 + quad * 8);
                a2[t] = __builtin_amdgcn_mfma_f32_16x16x32_bf16(Ah2.v, Bh2.v, a2[t], 0, 0, 0);
                a2[t] = __builtin_amdgcn_mfma_f32_16x16x32_bf16(Ah2.v, Bl2.v, a2[t], 0, 0, 0);
                a2[t] = __builtin_amdgcn_mfma_f32_16x16x32_bf16(Al2.v, Bh2.v, a2[t], 0, 0, 0);
            }
        }
#pragma unroll
        for (int t = 0; t < 3; t++) {
            int col = t * 16 + row16;
            if (col < C_CLS) {
                float bias = b2c[col];
#pragma unroll
                for (int r = 0; r < 4; r++) {
                    int grow = m0 + wave * 16 + quad * 4 + r;
                    if (grow < N_NODES) {
                        float v = a2[t][r] + bias;
                        v = v > 0.f ? v : 0.f;
                        H2[(size_t)grow * C_CLS + col] = v;
                        Za[(size_t)grow * C_CLS + col] = v;
                    }
                }
            }
        }
    }
}

// ---------------------------------------------------------------- CSR build
__global__ void deg_kernel(const int* __restrict__ ei, const int* __restrict__ flags,
                           int* __restrict__ deg) {
    int e = blockIdx.x * blockDim.x + threadIdx.x;
    if (e < E_EDGES) {
        int d = (flags[2] != 0) ? ei[E_EDGES + e] : ei[2 * (E_EDGES + e)];
        if ((unsigned)d < N_NODES) atomicAdd(&deg[d], 1);
    }
}

__global__ void dinv_kernel(const int* __restrict__ deg, float* __restrict__ dinv) {
    int i = blockIdx.x * blockDim.x + threadIdx.x;
    if (i < N_NODES) dinv[i] = 1.0f / sqrtf((float)(deg[i] + 1));   // +1 self loop
}

__global__ __launch_bounds__(256) void scan_block_kernel(
    const int* __restrict__ deg, int* __restrict__ rowstart, int* __restrict__ blockSums)
{
    __shared__ int sdata[256];
    const int tid = threadIdx.x;
    const int base = blockIdx.x * 1024 + tid * 4;
    int v[4];
    int s = 0;
#pragma unroll
    for (int j = 0; j < 4; j++) {
        int i = base + j;
        v[j] = (i < N_NODES) ? deg[i] : 0;
        s += v[j];
    }
    sdata[tid] = s;
    __syncthreads();
    int t = s;
    for (int off = 1; off < 256; off <<= 1) {
        int x = (tid >= off) ? sdata[tid - off] : 0;
        __syncthreads();
        t += x;
        sdata[tid] = t;
        __syncthreads();
    }
    int run = t - s;
#pragma unroll
    for (int j = 0; j < 4; j++) {
        int i = base + j;
        if (i < N_NODES) rowstart[i] = run;
        run += v[j];
    }
    if (tid == 0) blockSums[blockIdx.x] = sdata[255];
}

__global__ void scan_top_kernel(int* __restrict__ blockSums, int nb) {
    if (threadIdx.x == 0 && blockIdx.x == 0) {
        int run = 0;
        for (int i = 0; i < nb; i++) { int v = blockSums[i]; blockSums[i] = run; run += v; }
    }
}

__global__ void scan_add_kernel(int* __restrict__ rowstart, const int* __restrict__ blockSums) {
    int i = blockIdx.x * blockDim.x + threadIdx.x;
    if (i < N_NODES) rowstart[i] += blockSums[i >> 10];
}

__global__ void scatter_kernel(const int* __restrict__ ei, const int* __restrict__ flags,
                               const float* __restrict__ dinv,
                               const int* __restrict__ rowstart, int* __restrict__ cursor,
                               int2* __restrict__ csr)
{
    int e = blockIdx.x * blockDim.x + threadIdx.x;
    if (e < E_EDGES) {
        bool e32 = flags[2] != 0;
        int s = e32 ? ei[e] : ei[2 * e];
        int d = e32 ? ei[E_EDGES + e] : ei[2 * (E_EDGES + e)];
        if ((unsigned)s < N_NODES && (unsigned)d < N_NODES) {
            int pos = rowstart[d] + atomicAdd(&cursor[d], 1);
            int2 ent;
            ent.x = s;
            ent.y = __float_as_int(dinv[s] * dinv[d]);
            csr[pos] = ent;
        }
    }
}

// ---------------------------------------------------------------- propagation
// one wave per node, lanes 0..39 = classes; self loop analytic
__global__ __launch_bounds__(256) void prop_kernel(
    const int2* __restrict__ csr, const int* __restrict__ rowstart,
    const int* __restrict__ deg, const float* __restrict__ dinv,
    const float* __restrict__ h2,
    const float* __restrict__ zin, float* __restrict__ zout)
{
    int node = blockIdx.x * 4 + (threadIdx.x >> 6);
    int c = threadIdx.x & 63;
    if (node >= N_NODES || c >= C_CLS) return;
    int start = rowstart[node];
    int cnt   = deg[node];
    float di  = dinv[node];
    float sum = di * di * zin[(size_t)node * C_CLS + c];
    for (int j = 0; j < cnt; j++) {
        int2 e = csr[start + j];
        unsigned s = (unsigned)e.x;
        if (s >= N_NODES) s = 0;                        // defensive
        sum += __int_as_float(e.y) * zin[(size_t)s * C_CLS + c];
    }
    zout[(size_t)node * C_CLS + c] = 0.9f * sum + 0.1f * h2[(size_t)node * C_CLS + c];
}

__global__ void out_kernel(const float* __restrict__ z, const int* __restrict__ flags,
                           void* __restrict__ out) {
    int i = blockIdx.x * blockDim.x + threadIdx.x;
    if (i < N_NODES * C_CLS) {
        if (flags[0]) ((float*)out)[i] = z[i];
        else          ((unsigned short*)out)[i] = f2bf(z[i]);
    }
}

// ---------------------------------------------------------------- launch
extern "C" void kernel_launch(void* const* d_in, const int* in_sizes, int n_in,
                              void* d_out, int out_size, void* d_ws, size_t ws_size,
                              hipStream_t stream)
{
    const void* X  = d_in[0];
    const int*  EI = (const int*)d_in[1];
    const void* W1 = d_in[2];
    const void* B1 = d_in[3];
    const void* W2 = d_in[4];
    const void* B2 = d_in[5];

    char* ws = (char*)d_ws;
    size_t off = 0;
    auto alloc = [&](size_t bytes) -> void* {
        void* p = ws + off;
        off += (bytes + 255) & ~(size_t)255;
        return p;
    };
    // total ~61.5 MB
    float* H2 = (float*)alloc((size_t)N_NODES * C_CLS * 4);
    float* Za = (float*)alloc((size_t)N_NODES * C_CLS * 4);
    float* Zb = (float*)alloc((size_t)N_NODES * C_CLS * 4);
    int2*  csr = (int2*)alloc((size_t)E_EDGES * 8);
    unsigned short* W1T_hi = (unsigned short*)alloc(131072 * 2);
    unsigned short* W1T_lo = (unsigned short*)alloc(131072 * 2);
    unsigned short* W2T_hi = (unsigned short*)alloc(12288 * 2);
    unsigned short* W2T_lo = (unsigned short*)alloc(12288 * 2);
    float* b1c = (float*)alloc(256 * 4);
    float* b2c = (float*)alloc(48 * 4);
    int*   deg      = (int*)alloc((size_t)N_NODES * 4);
    float* dinv     = (float*)alloc((size_t)N_NODES * 4);
    int*   rowstart = (int*)alloc((size_t)N_NODES * 4);
    int*   cursor   = (int*)alloc((size_t)N_NODES * 4);
    int*   blockSums = (int*)alloc(128 * 4);
    int*   flags     = (int*)alloc(8 * 4);

    hipMemsetAsync(deg, 0, (size_t)N_NODES * 4, stream);
    hipMemsetAsync(cursor, 0, (size_t)N_NODES * 4, stream);

    sniff_kernel<<<1, 256, 0, stream>>>((const unsigned*)X, (const unsigned*)W1,
                                        (const unsigned*)EI, flags);
    canonw_kernel<<<562, 256, 0, stream>>>(W1, W2, B1, B2, flags,
                                           W1T_hi, W1T_lo, W2T_hi, W2T_lo, b1c, b2c);

    deg_kernel<<<(E_EDGES + 255) / 256, 256, 0, stream>>>(EI, flags, deg);
    dinv_kernel<<<(N_NODES + 255) / 256, 256, 0, stream>>>(deg, dinv);
    const int nscan = (N_NODES + 1023) / 1024;   // 98
    scan_block_kernel<<<nscan, 256, 0, stream>>>(deg, rowstart, blockSums);
    scan_top_kernel<<<1, 64, 0, stream>>>(blockSums, nscan);
    scan_add_kernel<<<(N_NODES + 255) / 256, 256, 0, stream>>>(rowstart, blockSums);
    scatter_kernel<<<(E_EDGES + 255) / 256, 256, 0, stream>>>(EI, flags, dinv, rowstart, cursor, csr);

    mlp48_kernel<<<(N_NODES + 47) / 48, 256, 0, stream>>>(X, W1T_hi, W1T_lo, W2T_hi, W2T_lo,
                                                          b1c, b2c, flags, H2, Za);

    // APPNP: Za -> Zb -> Za -> ... (H2 preserved for teleport)
    const float* zin = Za;
    float* bufs[2] = {Zb, Za};
    for (int s = 0; s < K_STEPS; s++) {
        float* zout = bufs[s & 1];
        prop_kernel<<<(N_NODES + 3) / 4, 256, 0, stream>>>(csr, rowstart, deg, dinv, H2, zin, zout);
        zin = zout;
    }

    out_kernel<<<(N_NODES * C_CLS + 255) / 256, 256, 0, stream>>>(zin, flags, d_out);
}

// Round 5
// 1139.744 us; speedup vs baseline: 1.9544x; 1.9544x over previous
//
#include <hip/hip_runtime.h>
#include <hip/hip_bf16.h>

#define N_NODES 100000
#define F_IN    512
#define HID     256
#define C_CLS   40
#define E_EDGES 1600000
#define K_STEPS 10

typedef __attribute__((ext_vector_type(8))) short bf16x8;
typedef __attribute__((ext_vector_type(4))) float f32x4;

union frag8 { bf16x8 v; unsigned short u[8]; uint4 q; };

__device__ inline unsigned short f2bf(float v) {
    union { __hip_bfloat16 b; unsigned short u; } c;
    c.b = __float2bfloat16(v);
    return c.u;
}
__device__ inline float bf2f(unsigned short u) {
    union { __hip_bfloat16 b; unsigned short u; } c;
    c.u = u;
    return __bfloat162float(c.b);
}
// split fp32 -> hi + lo bf16 (RNE both): v ~= hi + lo, err ~2^-17|v|
__device__ inline void splitbf(float v, unsigned short& hi, unsigned short& lo) {
    hi = f2bf(v);
    lo = f2bf(v - bf2f(hi));
}

// ---------------------------------------------------------------- dtype sniff
// flags[0]=x_is_f32  flags[1]=w_is_f32  flags[2]=edge_is_i32
__global__ void sniff_kernel(const unsigned* __restrict__ Xu,
                             const unsigned* __restrict__ W1u,
                             const unsigned* __restrict__ EIu,
                             int* __restrict__ flags)
{
    __shared__ int cnt[3];
    int t = threadIdx.x;
    if (t < 3) cnt[t] = 0;
    __syncthreads();
    unsigned xe = (Xu[t] >> 23) & 0xFF;
    if (xe >= 64 && xe <= 170) atomicAdd(&cnt[0], 1);
    unsigned we = (W1u[t] >> 23) & 0xFF;
    if (we >= 64 && we <= 170) atomicAdd(&cnt[1], 1);
    if (EIu[2 * t + 1] != 0) atomicAdd(&cnt[2], 1);
    __syncthreads();
    if (t == 0) {
        flags[0] = cnt[0] >= 200;
        flags[1] = cnt[1] >= 200;
        flags[2] = cnt[2] >= 8;
    }
}

// ---------------------------------------------------------------- canonical weights
// W1T tiled [k/8][256 cols][8]  (131072 elems), W2T tiled [k/8][48 cols][8] (12288)
// -> B-fragment loads are 256B-contiguous per 16-lane group.
__global__ void canonw_kernel(const void* __restrict__ W1_, const void* __restrict__ W2_,
                              const void* __restrict__ b1_, const void* __restrict__ b2_,
                              const int* __restrict__ flags,
                              unsigned short* __restrict__ W1T_hi, unsigned short* __restrict__ W1T_lo,
                              unsigned short* __restrict__ W2T_hi, unsigned short* __restrict__ W2T_lo,
                              float* __restrict__ b1c, float* __restrict__ b2c)
{
    const bool wf32 = flags[1] != 0;
    int i = blockIdx.x * 256 + threadIdx.x;
    if (i < 131072) {                       // W1T
        int n = i >> 9, k = i & 511;
        float v = wf32 ? ((const float*)W1_)[k * HID + n]
                       : bf2f(((const unsigned short*)W1_)[k * HID + n]);
        unsigned short hi, lo; splitbf(v, hi, lo);
        int idx = (k >> 3) * 2048 + n * 8 + (k & 7);
        W1T_hi[idx] = hi; W1T_lo[idx] = lo;
    }
    int j = i - 131072;
    if (j >= 0 && j < 48 * 256) {           // W2T
        int n = j >> 8, k = j & 255;
        float v = 0.f;
        if (n < C_CLS) v = wf32 ? ((const float*)W2_)[k * C_CLS + n]
                                : bf2f(((const unsigned short*)W2_)[k * C_CLS + n]);
        unsigned short hi, lo; splitbf(v, hi, lo);
        int idx = (k >> 3) * 384 + n * 8 + (k & 7);
        W2T_hi[idx] = hi; W2T_lo[idx] = lo;
    }
    int l = i - 131072 - 12288;
    if (l >= 0 && l < 256)
        b1c[l] = wf32 ? ((const float*)b1_)[l] : bf2f(((const unsigned short*)b1_)[l]);
    if (l >= 256 && l < 256 + 48) {
        int c = l - 256;
        b2c[c] = (c < C_CLS) ? (wf32 ? ((const float*)b2_)[c]
                                     : bf2f(((const unsigned short*)b2_)[c])) : 0.f;
    }
}

// ---------------------------------------------------------------- fused MLP (bf16x3)
// 48 rows/block; phase1: h1=relu(X@W1+b1) -> LDS hi/lo; phase2: relu(h1@W2+b2) -> H2,Za
// v2: register prefetch of next X k-chunk; tiled B layout (coalesced L2 reads).
__global__ __launch_bounds__(256) void mlp48_kernel(
    const void* __restrict__ X_,
    const unsigned short* __restrict__ W1T_hi, const unsigned short* __restrict__ W1T_lo,
    const unsigned short* __restrict__ W2T_hi, const unsigned short* __restrict__ W2T_lo,
    const float* __restrict__ b1c, const float* __restrict__ b2c,
    const int* __restrict__ flags,
    float* __restrict__ H2, float* __restrict__ Za)
{
    __shared__ __align__(16) unsigned short h1hi[48 * 264];
    __shared__ __align__(16) unsigned short h1lo[48 * 264];

    const int tid = threadIdx.x, lane = tid & 63, wave = tid >> 6;
    const int row16 = lane & 15, quad = lane >> 4;
    const int m0 = blockIdx.x * 48;
    const bool xf32 = flags[0] != 0;

    int gmr[3];
#pragma unroll
    for (int i = 0; i < 3; i++) {
        int gm = m0 + i * 16 + row16;
        gmr[i] = gm < N_NODES ? gm : N_NODES - 1;
    }

    f32x4 acc[3][4];
    const f32x4 z4 = {0.f, 0.f, 0.f, 0.f};
#pragma unroll
    for (int i = 0; i < 3; i++)
#pragma unroll
        for (int j = 0; j < 4; j++) acc[i][j] = z4;

    if (xf32) {
        const float* Xf = (const float*)X_;
        float4 nA[3][2];
#pragma unroll
        for (int i = 0; i < 3; i++) {
            const float* p = Xf + (size_t)gmr[i] * F_IN + quad * 8;
            nA[i][0] = *(const float4*)p;
            nA[i][1] = *(const float4*)(p + 4);
        }
        for (int k0 = 0; k0 < F_IN; k0 += 32) {
            float4 c0[3][2];
#pragma unroll
            for (int i = 0; i < 3; i++) { c0[i][0] = nA[i][0]; c0[i][1] = nA[i][1]; }
            if (k0 + 32 < F_IN) {
#pragma unroll
                for (int i = 0; i < 3; i++) {
                    const float* p = Xf + (size_t)gmr[i] * F_IN + k0 + 32 + quad * 8;
                    nA[i][0] = *(const float4*)p;
                    nA[i][1] = *(const float4*)(p + 4);
                }
            }
            frag8 Ah[3], Al[3], Bh[4], Bl[4];
            const int kb = ((k0 + quad * 8) >> 3) * 2048;
#pragma unroll
            for (int t = 0; t < 4; t++) {
                int col = wave * 64 + t * 16 + row16;
                Bh[t].q = *(const uint4*)(W1T_hi + kb + col * 8);
                Bl[t].q = *(const uint4*)(W1T_lo + kb + col * 8);
            }
#pragma unroll
            for (int i = 0; i < 3; i++) {
                float vv[8] = {c0[i][0].x, c0[i][0].y, c0[i][0].z, c0[i][0].w,
                               c0[i][1].x, c0[i][1].y, c0[i][1].z, c0[i][1].w};
#pragma unroll
                for (int j = 0; j < 8; j++) splitbf(vv[j], Ah[i].u[j], Al[i].u[j]);
            }
#pragma unroll
            for (int i = 0; i < 3; i++)
#pragma unroll
                for (int t = 0; t < 4; t++) {
                    acc[i][t] = __builtin_amdgcn_mfma_f32_16x16x32_bf16(Ah[i].v, Bh[t].v, acc[i][t], 0, 0, 0);
                    acc[i][t] = __builtin_amdgcn_mfma_f32_16x16x32_bf16(Ah[i].v, Bl[t].v, acc[i][t], 0, 0, 0);
                    acc[i][t] = __builtin_amdgcn_mfma_f32_16x16x32_bf16(Al[i].v, Bh[t].v, acc[i][t], 0, 0, 0);
                }
        }
    } else {
        for (int k0 = 0; k0 < F_IN; k0 += 32) {
            frag8 Ah[3], Al[3], Bh[4], Bl[4];
#pragma unroll
            for (int i = 0; i < 3; i++) {
                const unsigned short* p = (const unsigned short*)X_ + (size_t)gmr[i] * F_IN + k0 + quad * 8;
                Ah[i].q = *(const uint4*)p;
#pragma unroll
                for (int j = 0; j < 8; j++) Al[i].u[j] = 0;
            }
            const int kb = ((k0 + quad * 8) >> 3) * 2048;
#pragma unroll
            for (int t = 0; t < 4; t++) {
                int col = wave * 64 + t * 16 + row16;
                Bh[t].q = *(const uint4*)(W1T_hi + kb + col * 8);
                Bl[t].q = *(const uint4*)(W1T_lo + kb + col * 8);
            }
#pragma unroll
            for (int i = 0; i < 3; i++)
#pragma unroll
                for (int t = 0; t < 4; t++) {
                    acc[i][t] = __builtin_amdgcn_mfma_f32_16x16x32_bf16(Ah[i].v, Bh[t].v, acc[i][t], 0, 0, 0);
                    acc[i][t] = __builtin_amdgcn_mfma_f32_16x16x32_bf16(Ah[i].v, Bl[t].v, acc[i][t], 0, 0, 0);
                }
        }
    }

    // epilogue 1: bias+relu, split -> LDS. C/D: col=lane&15, row=quad*4+reg
#pragma unroll
    for (int j = 0; j < 4; j++) {
        int col = wave * 64 + j * 16 + row16;
        float bias = b1c[col];
#pragma unroll
        for (int i = 0; i < 3; i++)
#pragma unroll
            for (int r = 0; r < 4; r++) {
                int lm = i * 16 + quad * 4 + r;
                float v = acc[i][j][r] + bias;
                v = v > 0.f ? v : 0.f;
                unsigned short hi, lo; splitbf(v, hi, lo);
                h1hi[lm * 264 + col] = hi;
                h1lo[lm * 264 + col] = lo;
            }
    }
    __syncthreads();

    // phase 2: waves 0..2 -> rows wave*16..+15, cols 0..47
    if (wave < 3) {
        f32x4 a2[3];
        a2[0] = z4; a2[1] = z4; a2[2] = z4;
        for (int k0 = 0; k0 < HID; k0 += 32) {
            frag8 Ah2, Al2;
            Ah2.v = *(const bf16x8*)(h1hi + (wave * 16 + row16) * 264 + k0 + quad * 8);
            Al2.v = *(const bf16x8*)(h1lo + (wave * 16 + row16) * 264 + k0 + quad * 8);
            const int kb = ((k0 + quad * 8) >> 3) * 384;
#pragma unroll
            for (int t = 0; t < 3; t++) {
                frag8 Bh2, Bl2;
                Bh2.q = *(const uint4*)(W2T_hi + kb + (t * 16 + row16) * 8);
                Bl2.q = *(const uint4*)(W2T_lo + kb + (t * 16 + row16) * 8);
                a2[t] = __builtin_amdgcn_mfma_f32_16x16x32_bf16(Ah2.v, Bh2.v, a2[t], 0, 0, 0);
                a2[t] = __builtin_amdgcn_mfma_f32_16x16x32_bf16(Ah2.v, Bl2.v, a2[t], 0, 0, 0);
                a2[t] = __builtin_amdgcn_mfma_f32_16x16x32_bf16(Al2.v, Bh2.v, a2[t], 0, 0, 0);
            }
        }
#pragma unroll
        for (int t = 0; t < 3; t++) {
            int col = t * 16 + row16;
            if (col < C_CLS) {
                float bias = b2c[col];
#pragma unroll
                for (int r = 0; r < 4; r++) {
                    int grow = m0 + wave * 16 + quad * 4 + r;
                    if (grow < N_NODES) {
                        float v = a2[t][r] + bias;
                        v = v > 0.f ? v : 0.f;
                        H2[(size_t)grow * C_CLS + col] = v;
                        Za[(size_t)grow * C_CLS + col] = v;
                    }
                }
            }
        }
    }
}

// ---------------------------------------------------------------- CSR build
__global__ void deg_kernel(const int* __restrict__ ei, const int* __restrict__ flags,
                           int* __restrict__ deg) {
    int e = blockIdx.x * blockDim.x + threadIdx.x;
    if (e < E_EDGES) {
        bool e32 = flags[2] != 0;
        int s = e32 ? ei[e] : ei[2 * e];
        int d = e32 ? ei[E_EDGES + e] : ei[2 * (E_EDGES + e)];
        // count only edges scatter will write -> CSR rows always fully populated
        if ((unsigned)s < N_NODES && (unsigned)d < N_NODES) atomicAdd(&deg[d], 1);
    }
}

__global__ void dinv_kernel(const int* __restrict__ deg, float* __restrict__ dinv) {
    int i = blockIdx.x * blockDim.x + threadIdx.x;
    if (i < N_NODES) dinv[i] = 1.0f / sqrtf((float)(deg[i] + 1));   // +1 self loop
}

__global__ __launch_bounds__(256) void scan_block_kernel(
    const int* __restrict__ deg, int* __restrict__ rowstart, int* __restrict__ blockSums)
{
    __shared__ int sdata[256];
    const int tid = threadIdx.x;
    const int base = blockIdx.x * 1024 + tid * 4;
    int v[4];
    int s = 0;
#pragma unroll
    for (int j = 0; j < 4; j++) {
        int i = base + j;
        v[j] = (i < N_NODES) ? deg[i] : 0;
        s += v[j];
    }
    sdata[tid] = s;
    __syncthreads();
    int t = s;
    for (int off = 1; off < 256; off <<= 1) {
        int x = (tid >= off) ? sdata[tid - off] : 0;
        __syncthreads();
        t += x;
        sdata[tid] = t;
        __syncthreads();
    }
    int run = t - s;
#pragma unroll
    for (int j = 0; j < 4; j++) {
        int i = base + j;
        if (i < N_NODES) rowstart[i] = run;
        run += v[j];
    }
    if (tid == 0) blockSums[blockIdx.x] = sdata[255];
}

__global__ void scan_top_kernel(int* __restrict__ blockSums, int nb) {
    if (threadIdx.x == 0 && blockIdx.x == 0) {
        int run = 0;
        for (int i = 0; i < nb; i++) { int v = blockSums[i]; blockSums[i] = run; run += v; }
    }
}

__global__ void scan_add_kernel(int* __restrict__ rowstart, const int* __restrict__ blockSums) {
    int i = blockIdx.x * blockDim.x + threadIdx.x;
    if (i < N_NODES) rowstart[i] += blockSums[i >> 10];
}

__global__ void scatter_kernel(const int* __restrict__ ei, const int* __restrict__ flags,
                               const float* __restrict__ dinv,
                               const int* __restrict__ rowstart, int* __restrict__ cursor,
                               int2* __restrict__ csr)
{
    int e = blockIdx.x * blockDim.x + threadIdx.x;
    if (e < E_EDGES) {
        bool e32 = flags[2] != 0;
        int s = e32 ? ei[e] : ei[2 * e];
        int d = e32 ? ei[E_EDGES + e] : ei[2 * (E_EDGES + e)];
        if ((unsigned)s < N_NODES && (unsigned)d < N_NODES) {
            int pos = rowstart[d] + atomicAdd(&cursor[d], 1);
            int2 ent;
            ent.x = s;
            ent.y = __float_as_int(dinv[s] * dinv[d]);
            csr[pos] = ent;
        }
    }
}

// pack per-node info: start, cnt, dinv^2
__global__ void pack_kernel(const int* __restrict__ rowstart, const int* __restrict__ deg,
                            const float* __restrict__ dinv, int4* __restrict__ ninfo) {
    int i = blockIdx.x * blockDim.x + threadIdx.x;
    if (i < N_NODES) {
        float di = dinv[i];
        int4 v;
        v.x = rowstart[i];
        v.y = deg[i];
        v.z = __float_as_int(di * di);
        v.w = 0;
        ninfo[i] = v;
    }
}

// ---------------------------------------------------------------- propagation v3
// thread = (node, class-quad): 10 lanes x float4 per node; unroll-4 edge loop.
// 320 thr/block = 32 nodes exactly; grid 3125 = 1M threads = N*10 exactly.
__global__ __launch_bounds__(320) void prop4_kernel(
    const int2* __restrict__ csr, const int4* __restrict__ ninfo,
    const float4* __restrict__ h2, const float4* __restrict__ zin,
    float4* __restrict__ zout)
{
    int gid = blockIdx.x * 320 + threadIdx.x;
    int node = gid / 10;
    int part = gid - node * 10;
    if (node >= N_NODES) return;
    int4 ni = ninfo[node];
    const int start = ni.x;
    const int cnt   = ni.y;
    const float di2 = __int_as_float(ni.z);
    const int base  = node * 10 + part;

    float4 zown = zin[base];
    float4 sum;
    sum.x = di2 * zown.x; sum.y = di2 * zown.y;
    sum.z = di2 * zown.z; sum.w = di2 * zown.w;

    int j = 0;
    for (; j + 4 <= cnt; j += 4) {
        int2 e0 = csr[start + j];
        int2 e1 = csr[start + j + 1];
        int2 e2 = csr[start + j + 2];
        int2 e3 = csr[start + j + 3];
        float4 z0 = zin[(size_t)(unsigned)e0.x * 10 + part];
        float4 z1 = zin[(size_t)(unsigned)e1.x * 10 + part];
        float4 z2 = zin[(size_t)(unsigned)e2.x * 10 + part];
        float4 z3 = zin[(size_t)(unsigned)e3.x * 10 + part];
        float w0 = __int_as_float(e0.y), w1 = __int_as_float(e1.y);
        float w2 = __int_as_float(e2.y), w3 = __int_as_float(e3.y);
        sum.x = fmaf(w0, z0.x, sum.x); sum.y = fmaf(w0, z0.y, sum.y);
        sum.z = fmaf(w0, z0.z, sum.z); sum.w = fmaf(w0, z0.w, sum.w);
        sum.x = fmaf(w1, z1.x, sum.x); sum.y = fmaf(w1, z1.y, sum.y);
        sum.z = fmaf(w1, z1.z, sum.z); sum.w = fmaf(w1, z1.w, sum.w);
        sum.x = fmaf(w2, z2.x, sum.x); sum.y = fmaf(w2, z2.y, sum.y);
        sum.z = fmaf(w2, z2.z, sum.z); sum.w = fmaf(w2, z2.w, sum.w);
        sum.x = fmaf(w3, z3.x, sum.x); sum.y = fmaf(w3, z3.y, sum.y);
        sum.z = fmaf(w3, z3.z, sum.z); sum.w = fmaf(w3, z3.w, sum.w);
    }
    for (; j < cnt; j++) {
        int2 e = csr[start + j];
        float4 zv = zin[(size_t)(unsigned)e.x * 10 + part];
        float w = __int_as_float(e.y);
        sum.x = fmaf(w, zv.x, sum.x); sum.y = fmaf(w, zv.y, sum.y);
        sum.z = fmaf(w, zv.z, sum.z); sum.w = fmaf(w, zv.w, sum.w);
    }
    float4 h = h2[base];
    float4 o;
    o.x = 0.9f * sum.x + 0.1f * h.x;
    o.y = 0.9f * sum.y + 0.1f * h.y;
    o.z = 0.9f * sum.z + 0.1f * h.z;
    o.w = 0.9f * sum.w + 0.1f * h.w;
    zout[base] = o;
}

__global__ void out_kernel(const float* __restrict__ z, const int* __restrict__ flags,
                           void* __restrict__ out) {
    int i = blockIdx.x * blockDim.x + threadIdx.x;
    if (i < N_NODES * C_CLS) {
        if (flags[0]) ((float*)out)[i] = z[i];
        else          ((unsigned short*)out)[i] = f2bf(z[i]);
    }
}

// ---------------------------------------------------------------- launch
extern "C" void kernel_launch(void* const* d_in, const int* in_sizes, int n_in,
                              void* d_out, int out_size, void* d_ws, size_t ws_size,
                              hipStream_t stream)
{
    const void* X  = d_in[0];
    const int*  EI = (const int*)d_in[1];
    const void* W1 = d_in[2];
    const void* B1 = d_in[3];
    const void* W2 = d_in[4];
    const void* B2 = d_in[5];

    char* ws = (char*)d_ws;
    size_t off = 0;
    auto alloc = [&](size_t bytes) -> void* {
        void* p = ws + off;
        off += (bytes + 255) & ~(size_t)255;
        return p;
    };
    // total ~63 MB
    float* H2 = (float*)alloc((size_t)N_NODES * C_CLS * 4);
    float* Za = (float*)alloc((size_t)N_NODES * C_CLS * 4);
    float* Zb = (float*)alloc((size_t)N_NODES * C_CLS * 4);
    int2*  csr = (int2*)alloc((size_t)E_EDGES * 8);
    int4*  ninfo = (int4*)alloc((size_t)N_NODES * 16);
    unsigned short* W1T_hi = (unsigned short*)alloc(131072 * 2);
    unsigned short* W1T_lo = (unsigned short*)alloc(131072 * 2);
    unsigned short* W2T_hi = (unsigned short*)alloc(12288 * 2);
    unsigned short* W2T_lo = (unsigned short*)alloc(12288 * 2);
    float* b1c = (float*)alloc(256 * 4);
    float* b2c = (float*)alloc(48 * 4);
    int*   deg      = (int*)alloc((size_t)N_NODES * 4);
    float* dinv     = (float*)alloc((size_t)N_NODES * 4);
    int*   rowstart = (int*)alloc((size_t)N_NODES * 4);
    int*   cursor   = (int*)alloc((size_t)N_NODES * 4);
    int*   blockSums = (int*)alloc(128 * 4);
    int*   flags     = (int*)alloc(8 * 4);

    hipMemsetAsync(deg, 0, (size_t)N_NODES * 4, stream);
    hipMemsetAsync(cursor, 0, (size_t)N_NODES * 4, stream);

    sniff_kernel<<<1, 256, 0, stream>>>((const unsigned*)X, (const unsigned*)W1,
                                        (const unsigned*)EI, flags);
    canonw_kernel<<<562, 256, 0, stream>>>(W1, W2, B1, B2, flags,
                                           W1T_hi, W1T_lo, W2T_hi, W2T_lo, b1c, b2c);

    deg_kernel<<<(E_EDGES + 255) / 256, 256, 0, stream>>>(EI, flags, deg);
    dinv_kernel<<<(N_NODES + 255) / 256, 256, 0, stream>>>(deg, dinv);
    const int nscan = (N_NODES + 1023) / 1024;   // 98
    scan_block_kernel<<<nscan, 256, 0, stream>>>(deg, rowstart, blockSums);
    scan_top_kernel<<<1, 64, 0, stream>>>(blockSums, nscan);
    scan_add_kernel<<<(N_NODES + 255) / 256, 256, 0, stream>>>(rowstart, blockSums);
    scatter_kernel<<<(E_EDGES + 255) / 256, 256, 0, stream>>>(EI, flags, dinv, rowstart, cursor, csr);
    pack_kernel<<<(N_NODES + 255) / 256, 256, 0, stream>>>(rowstart, deg, dinv, ninfo);

    mlp48_kernel<<<(N_NODES + 47) / 48, 256, 0, stream>>>(X, W1T_hi, W1T_lo, W2T_hi, W2T_lo,
                                                          b1c, b2c, flags, H2, Za);

    // APPNP: Za -> Zb -> Za -> ... (H2 preserved for teleport)
    const float4* zin = (const float4*)Za;
    float4* bufs[2] = {(float4*)Zb, (float4*)Za};
    for (int s = 0; s < K_STEPS; s++) {
        float4* zout = bufs[s & 1];
        prop4_kernel<<<3125, 320, 0, stream>>>(csr, ninfo, (const float4*)H2, zin, zout);
        zin = zout;
    }

    out_kernel<<<(N_NODES * C_CLS + 255) / 256, 256, 0, stream>>>((const float*)zin, flags, d_out);
}